// Round 10
// baseline (476.124 us; speedup 1.0000x reference)
//
#include <hip/hip_runtime.h>

// Problem constants
#define B_  8192
#define L_  10
#define D_  128
#define H_  64
#define OUT_ 5

typedef _Float16 h2 __attribute__((ext_vector_type(2)));
typedef unsigned int uint;

// ws dword layout:
#define WS_ENCPK   0        // [kp<96][l]: uint4, dword q = half2(W[q*64+l][2kp], [2kp+1]); k<128: Wih, else Whh
#define WS_ENCB    24576    // 256 floats: [l][q] = bih+bhh
#define WS_DECY    24832    // [k<5][l]: float4 fp32 (dec Wih columns)
#define WS_DECPK   26112    // [ep<32][l]: uint4, half2(decWhh[q*64+l][2ep], [2ep+1])
#define WS_DECB    34304    // 256 floats
#define WS_W1HCP   34560    // [ep<32][l]: uint2 {half2 W1h pair, half2 W1c pair}
#define WS_W1XP    38656    // [ep<32][l]: uint half2 W1x pair
#define WS_G       40960    // uint2 G[(b*L+t)*64+l] = {h2(a0,a1), h2(a2,a3)}  (enc input-gates, bias folded)

__device__ __forceinline__ float sigmf(float x){ return 1.f/(1.f+__expf(-x)); }
__device__ __forceinline__ float tanhf_(float x){ return 1.f - 2.f/(1.f+__expf(2.f*x)); }
__device__ __forceinline__ uint bcastu(uint v, int lane){
  return (uint)__builtin_amdgcn_readlane((int)v, lane);
}
__device__ __forceinline__ float dot2(uint w, uint a, float acc){
  return __builtin_amdgcn_fdot2(__builtin_bit_cast(h2, w), __builtin_bit_cast(h2, a), acc, false);
}
__device__ __forceinline__ uint pack_rtz(float a, float b){
  return __builtin_bit_cast(uint, __builtin_amdgcn_cvt_pkrtz(a, b));
}
__device__ __forceinline__ uint pack_rtn(float a, float b){
  h2 v; v.x = (_Float16)a; v.y = (_Float16)b;
  return __builtin_bit_cast(uint, v);
}
__device__ __forceinline__ float2 unpk(uint u){
  h2 v = __builtin_bit_cast(h2, u);
  return make_float2((float)v.x, (float)v.y);
}

__global__ void prep_kernel(const float* __restrict__ encWih, const float* __restrict__ encWhh,
                            const float* __restrict__ encbih, const float* __restrict__ encbhh,
                            const float* __restrict__ decWih, const float* __restrict__ decWhh,
                            const float* __restrict__ decbih, const float* __restrict__ decbhh,
                            const float* __restrict__ w1, float* __restrict__ wsf)
{
  uint* ws = (uint*)wsf;
  int stride = gridDim.x * blockDim.x;
  int tid0 = blockIdx.x * blockDim.x + threadIdx.x;

  for (int idx = tid0; idx < 96*64; idx += stride) {
    int kp = idx >> 6, l = idx & 63;
    uint4 o; uint* op = (uint*)&o;
    #pragma unroll
    for (int q=0;q<4;++q){
      int j = q*64 + l;
      int k0 = 2*kp, k1 = 2*kp+1;
      float a = (k0 < 128) ? encWih[j*128 + k0] : encWhh[j*64 + (k0-128)];
      float b = (k1 < 128) ? encWih[j*128 + k1] : encWhh[j*64 + (k1-128)];
      op[q] = pack_rtn(a,b);
    }
    ((uint4*)(ws + WS_ENCPK))[idx] = o;
  }
  for (int idx = tid0; idx < 256; idx += stride) {
    int l = idx >> 2, q = idx & 3, j = q*64+l;
    wsf[WS_ENCB+idx] = encbih[j] + encbhh[j];
  }
  for (int idx = tid0; idx < 5*64; idx += stride) {
    int k = idx >> 6, l = idx & 63;
    float4 o;
    o.x = decWih[(0*64+l)*5 + k];
    o.y = decWih[(1*64+l)*5 + k];
    o.z = decWih[(2*64+l)*5 + k];
    o.w = decWih[(3*64+l)*5 + k];
    ((float4*)(wsf + WS_DECY))[idx] = o;
  }
  for (int idx = tid0; idx < 32*64; idx += stride) {
    int ep = idx >> 6, l = idx & 63;
    uint4 o; uint* op = (uint*)&o;
    #pragma unroll
    for (int q=0;q<4;++q){
      int j = q*64 + l;
      op[q] = pack_rtn(decWhh[j*64 + 2*ep], decWhh[j*64 + 2*ep+1]);
    }
    ((uint4*)(ws + WS_DECPK))[idx] = o;
  }
  for (int idx = tid0; idx < 256; idx += stride) {
    int l = idx >> 2, q = idx & 3, j = q*64+l;
    wsf[WS_DECB+idx] = decbih[j] + decbhh[j];
  }
  for (int idx = tid0; idx < 32*64; idx += stride) {
    int ep = idx >> 6, l = idx & 63;
    uint2 o;
    o.x = pack_rtn(w1[l*192 + 2*ep],      w1[l*192 + 2*ep+1]);
    o.y = pack_rtn(w1[l*192 + 64 + 2*ep], w1[l*192 + 64 + 2*ep+1]);
    ((uint2*)(ws + WS_W1HCP))[idx] = o;
  }
  for (int idx = tid0; idx < 32*64; idx += stride) {
    int ep = idx >> 6, l = idx & 63;
    ws[WS_W1XP + idx] = pack_rtn(w1[l*192 + 128 + 2*ep], w1[l*192 + 128 + 2*ep+1]);
  }
}

// Parallel GEMM: G[b][t] = (at(b) ⊙ x[b,t]) @ encWih^T + bias.
// LDS-tiled: 64KB input-weight panel staged once per block (was the L2-BW bound:
// 2.6 GB of per-wave L2 re-streaming ≈ 76 µs). 4 waves × 4 rows = 16 rows/block.
__global__ __launch_bounds__(256, 2) void gemmG_kernel(
    const float* __restrict__ x, const float* __restrict__ enc_attn_w,
    const float* __restrict__ ws, uint2* __restrict__ Gp)
{
  __shared__ uint4 Wl[64*64];   // 64 KB
  const int l  = threadIdx.x & 63;
  const int wv = threadIdx.x >> 6;
  const int brow = blockIdx.x * 16 + wv*4;
  const int m2 = 2*(l&31);
  const uint4* encPk = (const uint4*)((const uint*)ws + WS_ENCPK);

  for (int i=threadIdx.x; i<64*64; i+=256) Wl[i]=encPk[i];
  __syncthreads();

  const float* xb[4];
  #pragma unroll
  for (int r=0;r<4;++r) xb[r] = x + (size_t)(brow+r)*(L_*D_);

  float at0[4], at1[4];
  #pragma unroll
  for (int r=0;r<4;++r){
    float s0=0.f,s1=0.f;
    #pragma unroll
    for (int t=0;t<L_;++t){
      float wx = enc_attn_w[2*H_ + t];
      s0 += xb[r][t*D_+l]*wx;
      s1 += xb[r][t*D_+64+l]*wx;
    }
    float m = fmaxf(s0,s1);
    for (int o=32;o;o>>=1) m = fmaxf(m, __shfl_xor(m,o));
    float e0=__expf(s0-m), e1=__expf(s1-m);
    float ss=e0+e1;
    for (int o=32;o;o>>=1) ss += __shfl_xor(ss,o);
    float inv = 1.f/ss;
    at0[r]=e0*inv; at1[r]=e1*inv;
  }
  float at0a[4],at0b[4],at1a[4],at1b[4];
  #pragma unroll
  for (int r=0;r<4;++r){
    at0a[r]=__shfl(at0[r],m2); at0b[r]=__shfl(at0[r],m2+1);
    at1a[r]=__shfl(at1[r],m2); at1b[r]=__shfl(at1[r],m2+1);
  }

  float4 bs = *(const float4*)(ws + WS_ENCB + l*4);

  for (int t=0;t<L_;++t){
    uint wi0p[4], wi1p[4];
    #pragma unroll
    for (int r=0;r<4;++r){
      float2 xp0 = *(const float2*)(xb[r] + t*D_ + m2);
      float2 xp1 = *(const float2*)(xb[r] + t*D_ + 64 + m2);
      wi0p[r]=pack_rtz(at0a[r]*xp0.x, at0b[r]*xp0.y);
      wi1p[r]=pack_rtz(at1a[r]*xp1.x, at1b[r]*xp1.y);
    }
    float a0[4],a1[4],a2[4],a3[4];
    #pragma unroll
    for (int r=0;r<4;++r){ a0[r]=bs.x;a1[r]=bs.y;a2[r]=bs.z;a3[r]=bs.w; }
    #pragma unroll 2
    for (int kp=0; kp<32; ++kp){
      uint4 w = Wl[kp*64+l];
      #pragma unroll
      for (int r=0;r<4;++r){
        uint u = bcastu(wi0p[r], kp);
        a0[r]=dot2(w.x,u,a0[r]); a1[r]=dot2(w.y,u,a1[r]);
        a2[r]=dot2(w.z,u,a2[r]); a3[r]=dot2(w.w,u,a3[r]);
      }
    }
    #pragma unroll 2
    for (int kp=0; kp<32; ++kp){
      uint4 w = Wl[(32+kp)*64+l];
      #pragma unroll
      for (int r=0;r<4;++r){
        uint u = bcastu(wi1p[r], kp);
        a0[r]=dot2(w.x,u,a0[r]); a1[r]=dot2(w.y,u,a1[r]);
        a2[r]=dot2(w.z,u,a2[r]); a3[r]=dot2(w.w,u,a3[r]);
      }
    }
    #pragma unroll
    for (int r=0;r<4;++r)
      Gp[((size_t)(brow+r)*L_+t)*64 + l] =
        make_uint2(pack_rtn(a0[r],a1[r]), pack_rtn(a2[r],a3[r]));
  }
}

#define R 2   // batch rows per wave (grid = 1024 blocks)

// VGPR target <=64 (4 waves/SIMD class): no sc[] array (unshifted exp is safe:
// |score| <= sum|w2| ~ 3), pre packed as f16 pairs, y_tilde fused into gate acc.
__global__ __launch_bounds__(256, 4) void darnn_kernel(
    const float* __restrict__ y_hist,
    const float* __restrict__ h0e, const float* __restrict__ c0e,
    const float* __restrict__ h0d, const float* __restrict__ c0d,
    const float* __restrict__ dec_attn_b1, const float* __restrict__ dec_attn_w2,
    const float* __restrict__ fc_w, const float* __restrict__ fc_b,
    const float* __restrict__ fcout_w, const float* __restrict__ fcout_b,
    const float* __restrict__ ws, const uint2* __restrict__ Gp,
    float* __restrict__ out)
{
  const int l  = threadIdx.x & 63;
  const int wv = threadIdx.x >> 6;
  const int brow = blockIdx.x * (4*R) + wv*R;
  const int m2 = 2*(l&31);

  const uint4*  encPk = (const uint4*)((const uint*)ws + WS_ENCPK);
  const float4* decY  = (const float4*)(ws + WS_DECY);
  const uint4*  decPk = (const uint4*)((const uint*)ws + WS_DECPK);
  const uint2*  w1hcp = (const uint2*)((const uint*)ws + WS_W1HCP);
  const uint*   w1xp  = (const uint*)ws + WS_W1XP;

  float h[R], c[R];
  #pragma unroll
  for (int r=0;r<R;++r){
    h[r]=h0e[(brow+r)*64+l];
    c[r]=c0e[(brow+r)*64+l];
  }

  float xe[R][L_];

  // -------- Encoder: recurrent part only (input gates precomputed in G) --------
  {
    uint2 g0 = Gp[((size_t)(brow+0)*L_+0)*64+l];
    uint2 g1 = Gp[((size_t)(brow+1)*L_+0)*64+l];
    for (int t=0;t<L_;++t){
      uint2 cg0=g0, cg1=g1;
      if (t+1<L_){
        g0 = Gp[((size_t)(brow+0)*L_+(t+1))*64+l];
        g1 = Gp[((size_t)(brow+1)*L_+(t+1))*64+l];
      }
      uint hp[R];
      #pragma unroll
      for (int r=0;r<R;++r)
        hp[r]=pack_rtz(__shfl(h[r],m2), __shfl(h[r],m2+1));
      float2 u00=unpk(cg0.x), u01=unpk(cg0.y), u10=unpk(cg1.x), u11=unpk(cg1.y);
      float a0[R]={u00.x,u10.x}, a1[R]={u00.y,u10.y};
      float a2[R]={u01.x,u11.x}, a3[R]={u01.y,u11.y};
      #pragma unroll 4
      for (int kp=0; kp<32; ++kp){
        uint4 w = encPk[(64+kp)*64+l];
        #pragma unroll
        for (int r=0;r<R;++r){
          uint u = bcastu(hp[r], kp);
          a0[r]=dot2(w.x,u,a0[r]); a1[r]=dot2(w.y,u,a1[r]);
          a2[r]=dot2(w.z,u,a2[r]); a3[r]=dot2(w.w,u,a3[r]);
        }
      }
      #pragma unroll
      for (int r=0;r<R;++r){
        float ig=sigmf(a0[r]), fg=sigmf(a1[r]), gg=tanhf_(a2[r]), og=sigmf(a3[r]);
        c[r]=fg*c[r]+ig*gg;
        h[r]=og*tanhf_(c[r]);
        xe[r][t]=h[r];
      }
    }
  }

  // preP[r][i] = f16 pair (pre[2i], pre[2i+1]);  pre[lt] = sum_e xe[lt](e)*W1x[l][e]
  uint preP[R][5];
  for (int r=0;r<R;++r){
    uint xep[L_];
    #pragma unroll
    for (int lt=0;lt<L_;++lt)
      xep[lt]=pack_rtz(__shfl(xe[r][lt],m2), __shfl(xe[r][lt],m2+1));
    float pr[L_];
    #pragma unroll
    for (int lt=0;lt<L_;++lt) pr[lt]=0.f;
    #pragma unroll 2
    for (int ep=0;ep<32;++ep){
      uint w = w1xp[ep*64+l];
      #pragma unroll
      for (int lt=0;lt<L_;++lt)
        pr[lt] = dot2(w, bcastu(xep[lt], ep), pr[lt]);
    }
    #pragma unroll
    for (int i=0;i<5;++i) preP[r][i]=pack_rtn(pr[2*i], pr[2*i+1]);
  }

  // ---------------- Decoder ----------------
  #pragma unroll
  for (int r=0;r<R;++r){
    h[r]=h0d[(brow+r)*64+l];
    c[r]=c0d[(brow+r)*64+l];
  }
  float b1l = dec_attn_b1[l];
  float w2l = dec_attn_w2[l];
  float ctx[R];
  #pragma unroll
  for (int r=0;r<R;++r) ctx[r]=0.f;

  const float* yb0 = y_hist + (size_t)(brow+0)*(L_*OUT_);
  const float* yb1 = y_hist + (size_t)(brow+1)*(L_*OUT_);

  for (int t=0;t<L_;++t){
    uint hp[R], cp[R];
    #pragma unroll
    for (int r=0;r<R;++r){
      hp[r]=pack_rtz(__shfl(h[r],m2), __shfl(h[r],m2+1));
      cp[r]=pack_rtz(__shfl(c[r],m2), __shfl(c[r],m2+1));
    }
    // vb[l] = b1[l] + sum_e h(e)W1h[l][e] + c(e)W1c[l][e]
    float vb[R];
    #pragma unroll
    for (int r=0;r<R;++r) vb[r]=b1l;
    #pragma unroll 4
    for (int ep=0;ep<32;++ep){
      uint2 w = w1hcp[ep*64+l];
      #pragma unroll
      for (int r=0;r<R;++r){
        vb[r]=dot2(w.x, bcastu(hp[r],ep), vb[r]);
        vb[r]=dot2(w.y, bcastu(cp[r],ep), vb[r]);
      }
    }
    // scores -> softmax (no max-shift: |p| <= sum|w2| ~ 3) -> ctx
    #pragma unroll
    for (int r=0;r<R;++r){
      float ssum=0.f, cx=0.f;
      #pragma unroll
      for (int i=0;i<5;++i){
        float2 pz = unpk(preP[r][i]);
        {
          float z = tanhf_(pz.x+vb[r]);
          float p = z*w2l;
          for (int o=32;o;o>>=1) p += __shfl_xor(p,o);
          float e = __expf(p);
          ssum += e; cx += e*xe[r][2*i];
        }
        {
          float z = tanhf_(pz.y+vb[r]);
          float p = z*w2l;
          for (int o=32;o;o>>=1) p += __shfl_xor(p,o);
          float e = __expf(p);
          ssum += e; cx += e*xe[r][2*i+1];
        }
      }
      ctx[r]=cx*(1.f/ssum);
    }
    // gates: y_tilde fused directly into the gate accumulators
    float4 bs = *(const float4*)(ws + WS_DECB + l*4);
    float a0[R],a1[R],a2[R],a3[R];
    #pragma unroll
    for (int r=0;r<R;++r){ a0[r]=bs.x;a1[r]=bs.y;a2[r]=bs.z;a3[r]=bs.w; }
    #pragma unroll
    for (int o2=0;o2<OUT_;++o2){
      float4 w = decY[o2*64+l];
      float fwl = fc_w[o2*69+l];
      float fb  = fc_b[o2];
      #pragma unroll
      for (int r=0;r<R;++r){
        const float* yb = (r==0)?yb0:yb1;
        float p = ctx[r]*fwl;
        for (int o=32;o;o>>=1) p += __shfl_xor(p,o);
        p += fb;
        #pragma unroll
        for (int j=0;j<OUT_;++j) p += yb[t*OUT_+j]*fc_w[o2*69+64+j];
        a0[r]+=p*w.x; a1[r]+=p*w.y; a2[r]+=p*w.z; a3[r]+=p*w.w;
      }
    }
    #pragma unroll 4
    for (int ep=0;ep<32;++ep){
      uint4 w = decPk[ep*64+l];
      #pragma unroll
      for (int r=0;r<R;++r){
        uint u = bcastu(hp[r], ep);
        a0[r]=dot2(w.x,u,a0[r]); a1[r]=dot2(w.y,u,a1[r]);
        a2[r]=dot2(w.z,u,a2[r]); a3[r]=dot2(w.w,u,a3[r]);
      }
    }
    #pragma unroll
    for (int r=0;r<R;++r){
      float ig=sigmf(a0[r]), fg=sigmf(a1[r]), gg=tanhf_(a2[r]), og=sigmf(a3[r]);
      c[r]=fg*c[r]+ig*gg;
      h[r]=og*tanhf_(c[r]);
    }
  }

  // out epilogue
  #pragma unroll
  for (int o2=0;o2<OUT_;++o2){
    float wa=fcout_w[o2*128+l];
    float wb=fcout_w[o2*128+64+l];
    float fb=fcout_b[o2];
    #pragma unroll
    for (int r=0;r<R;++r){
      float p = h[r]*wa + ctx[r]*wb;
      for (int o=32;o;o>>=1) p += __shfl_xor(p,o);
      if (l==o2) out[(size_t)(brow+r)*OUT_+o2] = p+fb;
    }
  }
}

extern "C" void kernel_launch(void* const* d_in, const int* in_sizes, int n_in,
                              void* d_out, int out_size, void* d_ws, size_t ws_size,
                              hipStream_t stream) {
  const float* x          = (const float*)d_in[0];
  const float* y_hist     = (const float*)d_in[1];
  const float* h0_enc     = (const float*)d_in[2];
  const float* c0_enc     = (const float*)d_in[3];
  const float* h0_dec     = (const float*)d_in[4];
  const float* c0_dec     = (const float*)d_in[5];
  const float* enc_attn_w = (const float*)d_in[6];
  const float* enc_Wih    = (const float*)d_in[8];
  const float* enc_Whh    = (const float*)d_in[9];
  const float* enc_bih    = (const float*)d_in[10];
  const float* enc_bhh    = (const float*)d_in[11];
  const float* dec_attn_w1= (const float*)d_in[12];
  const float* dec_attn_b1= (const float*)d_in[13];
  const float* dec_attn_w2= (const float*)d_in[14];
  const float* dec_Wih    = (const float*)d_in[16];
  const float* dec_Whh    = (const float*)d_in[17];
  const float* dec_bih    = (const float*)d_in[18];
  const float* dec_bhh    = (const float*)d_in[19];
  const float* fc_w       = (const float*)d_in[20];
  const float* fc_b       = (const float*)d_in[21];
  const float* fcout_w    = (const float*)d_in[22];
  const float* fcout_b    = (const float*)d_in[23];
  float* ws = (float*)d_ws;
  float* out = (float*)d_out;
  uint2* Gp = (uint2*)((uint*)d_ws + WS_G);

  hipLaunchKernelGGL(prep_kernel, dim3(128), dim3(256), 0, stream,
                     enc_Wih, enc_Whh, enc_bih, enc_bhh,
                     dec_Wih, dec_Whh, dec_bih, dec_bhh,
                     dec_attn_w1, ws);
  hipLaunchKernelGGL(gemmG_kernel, dim3(B_/16), dim3(256), 0, stream,
                     x, enc_attn_w, ws, Gp);
  hipLaunchKernelGGL(darnn_kernel, dim3(B_/(4*R)), dim3(256), 0, stream,
                     y_hist, h0_enc, c0_enc, h0_dec, c0_dec,
                     dec_attn_b1, dec_attn_w2,
                     fc_w, fc_b, fcout_w, fcout_b, ws, Gp, out);
}

// Round 11
// 422.185 us; speedup vs baseline: 1.1278x; 1.1278x over previous
//
#include <hip/hip_runtime.h>

// Problem constants
#define B_  8192
#define L_  10
#define D_  128
#define H_  64
#define OUT_ 5

typedef _Float16 h2 __attribute__((ext_vector_type(2)));
typedef unsigned int uint;

// ws dword layout:
#define WS_ENCPK   0        // [kp<96][l]: uint4, dword q = half2(W[q*64+l][2kp], [2kp+1]); k<128: Wih, else Whh
#define WS_ENCB    24576    // 256 floats: [l][q] = bih+bhh
#define WS_DECY    24832    // [k<5][l]: float4 fp32 (dec Wih columns)
#define WS_DECPK   26112    // [ep<32][l]: uint4, half2(decWhh[q*64+l][2ep], [2ep+1])
#define WS_DECB    34304    // 256 floats
#define WS_W1HCP   34560    // [ep<32][l]: uint2 {half2 W1h pair, half2 W1c pair}
#define WS_W1XP    38656    // [ep<32][l]: uint half2 W1x pair
#define WS_G       40960    // uint2 G[(b*L+t)*64+l] = {h2(a0,a1), h2(a2,a3)}  (enc input-gates, bias folded)

__device__ __forceinline__ float sigmf(float x){ return 1.f/(1.f+__expf(-x)); }
__device__ __forceinline__ float tanhf_(float x){ return 1.f - 2.f/(1.f+__expf(2.f*x)); }
__device__ __forceinline__ uint bcastu(uint v, int lane){
  return (uint)__builtin_amdgcn_readlane((int)v, lane);
}
__device__ __forceinline__ float dot2(uint w, uint a, float acc){
  return __builtin_amdgcn_fdot2(__builtin_bit_cast(h2, w), __builtin_bit_cast(h2, a), acc, false);
}
__device__ __forceinline__ uint pack_rtz(float a, float b){
  return __builtin_bit_cast(uint, __builtin_amdgcn_cvt_pkrtz(a, b));
}
__device__ __forceinline__ uint pack_rtn(float a, float b){
  h2 v; v.x = (_Float16)a; v.y = (_Float16)b;
  return __builtin_bit_cast(uint, v);
}
__device__ __forceinline__ float2 unpk(uint u){
  h2 v = __builtin_bit_cast(h2, u);
  return make_float2((float)v.x, (float)v.y);
}

__global__ void prep_kernel(const float* __restrict__ encWih, const float* __restrict__ encWhh,
                            const float* __restrict__ encbih, const float* __restrict__ encbhh,
                            const float* __restrict__ decWih, const float* __restrict__ decWhh,
                            const float* __restrict__ decbih, const float* __restrict__ decbhh,
                            const float* __restrict__ w1, float* __restrict__ wsf)
{
  uint* ws = (uint*)wsf;
  int stride = gridDim.x * blockDim.x;
  int tid0 = blockIdx.x * blockDim.x + threadIdx.x;

  for (int idx = tid0; idx < 96*64; idx += stride) {
    int kp = idx >> 6, l = idx & 63;
    uint4 o; uint* op = (uint*)&o;
    #pragma unroll
    for (int q=0;q<4;++q){
      int j = q*64 + l;
      int k0 = 2*kp, k1 = 2*kp+1;
      float a = (k0 < 128) ? encWih[j*128 + k0] : encWhh[j*64 + (k0-128)];
      float b = (k1 < 128) ? encWih[j*128 + k1] : encWhh[j*64 + (k1-128)];
      op[q] = pack_rtn(a,b);
    }
    ((uint4*)(ws + WS_ENCPK))[idx] = o;
  }
  for (int idx = tid0; idx < 256; idx += stride) {
    int l = idx >> 2, q = idx & 3, j = q*64+l;
    wsf[WS_ENCB+idx] = encbih[j] + encbhh[j];
  }
  for (int idx = tid0; idx < 5*64; idx += stride) {
    int k = idx >> 6, l = idx & 63;
    float4 o;
    o.x = decWih[(0*64+l)*5 + k];
    o.y = decWih[(1*64+l)*5 + k];
    o.z = decWih[(2*64+l)*5 + k];
    o.w = decWih[(3*64+l)*5 + k];
    ((float4*)(wsf + WS_DECY))[idx] = o;
  }
  for (int idx = tid0; idx < 32*64; idx += stride) {
    int ep = idx >> 6, l = idx & 63;
    uint4 o; uint* op = (uint*)&o;
    #pragma unroll
    for (int q=0;q<4;++q){
      int j = q*64 + l;
      op[q] = pack_rtn(decWhh[j*64 + 2*ep], decWhh[j*64 + 2*ep+1]);
    }
    ((uint4*)(ws + WS_DECPK))[idx] = o;
  }
  for (int idx = tid0; idx < 256; idx += stride) {
    int l = idx >> 2, q = idx & 3, j = q*64+l;
    wsf[WS_DECB+idx] = decbih[j] + decbhh[j];
  }
  for (int idx = tid0; idx < 32*64; idx += stride) {
    int ep = idx >> 6, l = idx & 63;
    uint2 o;
    o.x = pack_rtn(w1[l*192 + 2*ep],      w1[l*192 + 2*ep+1]);
    o.y = pack_rtn(w1[l*192 + 64 + 2*ep], w1[l*192 + 64 + 2*ep+1]);
    ((uint2*)(ws + WS_W1HCP))[idx] = o;
  }
  for (int idx = tid0; idx < 32*64; idx += stride) {
    int ep = idx >> 6, l = idx & 63;
    ws[WS_W1XP + idx] = pack_rtn(w1[l*192 + 128 + 2*ep], w1[l*192 + 128 + 2*ep+1]);
  }
}

// Parallel GEMM: G[b][t] = (at(b) ⊙ x[b,t]) @ encWih^T + bias.
// t-chunked (2 steps per weight pass): weight L2 traffic halved, no LDS, no
// barrier, ~56 VGPR -> true 4-waves/SIMD class without spill. R=2, 1024 blocks.
__global__ __launch_bounds__(256, 4) void gemmG_kernel(
    const float* __restrict__ x, const float* __restrict__ enc_attn_w,
    const float* __restrict__ ws, uint2* __restrict__ Gp)
{
  const int l  = threadIdx.x & 63;
  const int wv = threadIdx.x >> 6;
  const int brow = blockIdx.x * 8 + wv*2;
  const int m2 = 2*(l&31);
  const uint4* encPk = (const uint4*)((const uint*)ws + WS_ENCPK);

  const float* xb0 = x + (size_t)(brow+0)*(L_*D_);
  const float* xb1 = x + (size_t)(brow+1)*(L_*D_);

  float at0[2], at1[2];
  #pragma unroll
  for (int r=0;r<2;++r){
    const float* xb = (r==0)?xb0:xb1;
    float s0=0.f,s1=0.f;
    #pragma unroll
    for (int t=0;t<L_;++t){
      float wx = enc_attn_w[2*H_ + t];
      s0 += xb[t*D_+l]*wx;
      s1 += xb[t*D_+64+l]*wx;
    }
    float m = fmaxf(s0,s1);
    for (int o=32;o;o>>=1) m = fmaxf(m, __shfl_xor(m,o));
    float e0=__expf(s0-m), e1=__expf(s1-m);
    float ss=e0+e1;
    for (int o=32;o;o>>=1) ss += __shfl_xor(ss,o);
    float inv = 1.f/ss;
    at0[r]=e0*inv; at1[r]=e1*inv;
  }
  float at0a[2],at0b[2],at1a[2],at1b[2];
  #pragma unroll
  for (int r=0;r<2;++r){
    at0a[r]=__shfl(at0[r],m2); at0b[r]=__shfl(at0[r],m2+1);
    at1a[r]=__shfl(at1[r],m2); at1b[r]=__shfl(at1[r],m2+1);
  }

  float4 bs = *(const float4*)(ws + WS_ENCB + l*4);

  for (int tc=0; tc<5; ++tc){
    const int t0 = 2*tc, t1 = 2*tc+1;
    // wi[tt][half][row]
    uint wiA[2][2], wiB[2][2];
    #pragma unroll
    for (int tt=0; tt<2; ++tt){
      const int t = (tt==0)?t0:t1;
      float2 x00 = *(const float2*)(xb0 + t*D_ + m2);
      float2 x01 = *(const float2*)(xb0 + t*D_ + 64 + m2);
      float2 x10 = *(const float2*)(xb1 + t*D_ + m2);
      float2 x11 = *(const float2*)(xb1 + t*D_ + 64 + m2);
      wiA[tt][0]=pack_rtz(at0a[0]*x00.x, at0b[0]*x00.y);
      wiB[tt][0]=pack_rtz(at1a[0]*x01.x, at1b[0]*x01.y);
      wiA[tt][1]=pack_rtz(at0a[1]*x10.x, at0b[1]*x10.y);
      wiB[tt][1]=pack_rtz(at1a[1]*x11.x, at1b[1]*x11.y);
    }
    float a0[2][2],a1[2][2],a2[2][2],a3[2][2];   // [tt][row]
    #pragma unroll
    for (int tt=0;tt<2;++tt)
      #pragma unroll
      for (int r=0;r<2;++r){ a0[tt][r]=bs.x;a1[tt][r]=bs.y;a2[tt][r]=bs.z;a3[tt][r]=bs.w; }
    #pragma unroll 2
    for (int kp=0; kp<32; ++kp){
      uint4 w = encPk[kp*64+l];
      #pragma unroll
      for (int tt=0;tt<2;++tt)
        #pragma unroll
        for (int r=0;r<2;++r){
          uint u = bcastu(wiA[tt][r], kp);
          a0[tt][r]=dot2(w.x,u,a0[tt][r]); a1[tt][r]=dot2(w.y,u,a1[tt][r]);
          a2[tt][r]=dot2(w.z,u,a2[tt][r]); a3[tt][r]=dot2(w.w,u,a3[tt][r]);
        }
    }
    #pragma unroll 2
    for (int kp=0; kp<32; ++kp){
      uint4 w = encPk[(32+kp)*64+l];
      #pragma unroll
      for (int tt=0;tt<2;++tt)
        #pragma unroll
        for (int r=0;r<2;++r){
          uint u = bcastu(wiB[tt][r], kp);
          a0[tt][r]=dot2(w.x,u,a0[tt][r]); a1[tt][r]=dot2(w.y,u,a1[tt][r]);
          a2[tt][r]=dot2(w.z,u,a2[tt][r]); a3[tt][r]=dot2(w.w,u,a3[tt][r]);
        }
    }
    #pragma unroll
    for (int tt=0;tt<2;++tt){
      const int t = (tt==0)?t0:t1;
      #pragma unroll
      for (int r=0;r<2;++r)
        Gp[((size_t)(brow+r)*L_+t)*64 + l] =
          make_uint2(pack_rtn(a0[tt][r],a1[tt][r]), pack_rtn(a2[tt][r],a3[tt][r]));
    }
  }
}

#define R 2   // batch rows per wave (grid = 1024 blocks)

// Round-9 proven body: 255 µs, VGPR 76, no spill. (64-VGPR squeeze spills — r10.)
__global__ __launch_bounds__(256, 2) void darnn_kernel(
    const float* __restrict__ y_hist,
    const float* __restrict__ h0e, const float* __restrict__ c0e,
    const float* __restrict__ h0d, const float* __restrict__ c0d,
    const float* __restrict__ dec_attn_b1, const float* __restrict__ dec_attn_w2,
    const float* __restrict__ fc_w, const float* __restrict__ fc_b,
    const float* __restrict__ fcout_w, const float* __restrict__ fcout_b,
    const float* __restrict__ ws, const uint2* __restrict__ Gp,
    float* __restrict__ out)
{
  const int l  = threadIdx.x & 63;
  const int wv = threadIdx.x >> 6;
  const int brow = blockIdx.x * (4*R) + wv*R;
  const int m2 = 2*(l&31);

  const uint4*  encPk = (const uint4*)((const uint*)ws + WS_ENCPK);
  const float4* decY  = (const float4*)(ws + WS_DECY);
  const uint4*  decPk = (const uint4*)((const uint*)ws + WS_DECPK);
  const uint2*  w1hcp = (const uint2*)((const uint*)ws + WS_W1HCP);
  const uint*   w1xp  = (const uint*)ws + WS_W1XP;

  float h[R], c[R];
  #pragma unroll
  for (int r=0;r<R;++r){
    h[r]=h0e[(brow+r)*64+l];
    c[r]=c0e[(brow+r)*64+l];
  }

  float xe[R][L_];

  // -------- Encoder: recurrent part only (input gates precomputed in G) --------
  {
    uint2 g0 = Gp[((size_t)(brow+0)*L_+0)*64+l];
    uint2 g1 = Gp[((size_t)(brow+1)*L_+0)*64+l];
    for (int t=0;t<L_;++t){
      uint2 cg0=g0, cg1=g1;
      if (t+1<L_){
        g0 = Gp[((size_t)(brow+0)*L_+(t+1))*64+l];
        g1 = Gp[((size_t)(brow+1)*L_+(t+1))*64+l];
      }
      uint hp[R];
      #pragma unroll
      for (int r=0;r<R;++r)
        hp[r]=pack_rtz(__shfl(h[r],m2), __shfl(h[r],m2+1));
      float2 u00=unpk(cg0.x), u01=unpk(cg0.y), u10=unpk(cg1.x), u11=unpk(cg1.y);
      float a0[R]={u00.x,u10.x}, a1[R]={u00.y,u10.y};
      float a2[R]={u01.x,u11.x}, a3[R]={u01.y,u11.y};
      #pragma unroll 4
      for (int kp=0; kp<32; ++kp){
        uint4 w = encPk[(64+kp)*64+l];
        #pragma unroll
        for (int r=0;r<R;++r){
          uint u = bcastu(hp[r], kp);
          a0[r]=dot2(w.x,u,a0[r]); a1[r]=dot2(w.y,u,a1[r]);
          a2[r]=dot2(w.z,u,a2[r]); a3[r]=dot2(w.w,u,a3[r]);
        }
      }
      #pragma unroll
      for (int r=0;r<R;++r){
        float ig=sigmf(a0[r]), fg=sigmf(a1[r]), gg=tanhf_(a2[r]), og=sigmf(a3[r]);
        c[r]=fg*c[r]+ig*gg;
        h[r]=og*tanhf_(c[r]);
        xe[r][t]=h[r];
      }
    }
  }

  // pre[r][lt] = sum_e xe[r][lt](e) * W1x[l][e]  via packed pairs
  float pre[R][L_];
  {
    uint xep[R][L_];
    #pragma unroll
    for (int r=0;r<R;++r)
      #pragma unroll
      for (int lt=0;lt<L_;++lt){
        xep[r][lt]=pack_rtz(__shfl(xe[r][lt],m2), __shfl(xe[r][lt],m2+1));
        pre[r][lt]=0.f;
      }
    #pragma unroll 2
    for (int ep=0;ep<32;++ep){
      uint w = w1xp[ep*64+l];
      #pragma unroll
      for (int r=0;r<R;++r)
        #pragma unroll
        for (int lt=0;lt<L_;++lt)
          pre[r][lt] = dot2(w, bcastu(xep[r][lt], ep), pre[r][lt]);
    }
  }

  // ---------------- Decoder ----------------
  #pragma unroll
  for (int r=0;r<R;++r){
    h[r]=h0d[(brow+r)*64+l];
    c[r]=c0d[(brow+r)*64+l];
  }
  float b1l = dec_attn_b1[l];
  float w2l = dec_attn_w2[l];
  float ctx[R];
  #pragma unroll
  for (int r=0;r<R;++r) ctx[r]=0.f;

  const float* yb0 = y_hist + (size_t)(brow+0)*(L_*OUT_);
  const float* yb1 = y_hist + (size_t)(brow+1)*(L_*OUT_);

  for (int t=0;t<L_;++t){
    uint hp[R], cp[R];
    #pragma unroll
    for (int r=0;r<R;++r){
      hp[r]=pack_rtz(__shfl(h[r],m2), __shfl(h[r],m2+1));
      cp[r]=pack_rtz(__shfl(c[r],m2), __shfl(c[r],m2+1));
    }
    // vb[l] = b1[l] + sum_e h(e)W1h[l][e] + c(e)W1c[l][e]
    float vb[R];
    #pragma unroll
    for (int r=0;r<R;++r) vb[r]=b1l;
    #pragma unroll 4
    for (int ep=0;ep<32;++ep){
      uint2 w = w1hcp[ep*64+l];
      #pragma unroll
      for (int r=0;r<R;++r){
        vb[r]=dot2(w.x, bcastu(hp[r],ep), vb[r]);
        vb[r]=dot2(w.y, bcastu(cp[r],ep), vb[r]);
      }
    }
    // scores -> softmax over L -> ctx
    float yt[R][OUT_];
    #pragma unroll
    for (int r=0;r<R;++r){
      float sc[L_];
      #pragma unroll
      for (int lt=0;lt<L_;++lt){
        float z = tanhf_(pre[r][lt]+vb[r]);
        float p = z*w2l;
        for (int o=32;o;o>>=1) p += __shfl_xor(p,o);
        sc[lt]=p;
      }
      float mx=sc[0];
      #pragma unroll
      for (int lt=1;lt<L_;++lt) mx=fmaxf(mx,sc[lt]);
      float ssum=0.f;
      #pragma unroll
      for (int lt=0;lt<L_;++lt){ sc[lt]=__expf(sc[lt]-mx); ssum+=sc[lt]; }
      float inv=1.f/ssum;
      float cx=0.f;
      #pragma unroll
      for (int lt=0;lt<L_;++lt) cx += sc[lt]*xe[r][lt];
      ctx[r]=cx*inv;
    }
    // y_tilde
    #pragma unroll
    for (int r=0;r<R;++r){
      const float* yb = (r==0)?yb0:yb1;
      float yin[OUT_];
      #pragma unroll
      for (int j=0;j<OUT_;++j) yin[j]=yb[t*OUT_+j];
      #pragma unroll
      for (int o2=0;o2<OUT_;++o2){
        float p = ctx[r]*fc_w[o2*69+l];
        for (int o=32;o;o>>=1) p += __shfl_xor(p,o);
        p += fc_b[o2];
        #pragma unroll
        for (int j=0;j<OUT_;++j) p += yin[j]*fc_w[o2*69+64+j];
        yt[r][o2]=p;
      }
    }
    // gates
    float4 bs = *(const float4*)(ws + WS_DECB + l*4);
    float a0[R],a1[R],a2[R],a3[R];
    #pragma unroll
    for (int r=0;r<R;++r){ a0[r]=bs.x;a1[r]=bs.y;a2[r]=bs.z;a3[r]=bs.w; }
    #pragma unroll
    for (int k=0;k<OUT_;++k){
      float4 w = decY[k*64+l];
      #pragma unroll
      for (int r=0;r<R;++r){
        float v = yt[r][k];
        a0[r]+=v*w.x;a1[r]+=v*w.y;a2[r]+=v*w.z;a3[r]+=v*w.w;
      }
    }
    #pragma unroll 4
    for (int ep=0;ep<32;++ep){
      uint4 w = decPk[ep*64+l];
      #pragma unroll
      for (int r=0;r<R;++r){
        uint u = bcastu(hp[r], ep);
        a0[r]=dot2(w.x,u,a0[r]); a1[r]=dot2(w.y,u,a1[r]);
        a2[r]=dot2(w.z,u,a2[r]); a3[r]=dot2(w.w,u,a3[r]);
      }
    }
    #pragma unroll
    for (int r=0;r<R;++r){
      float ig=sigmf(a0[r]), fg=sigmf(a1[r]), gg=tanhf_(a2[r]), og=sigmf(a3[r]);
      c[r]=fg*c[r]+ig*gg;
      h[r]=og*tanhf_(c[r]);
    }
  }

  // out epilogue
  #pragma unroll
  for (int o2=0;o2<OUT_;++o2){
    float wa=fcout_w[o2*128+l];
    float wb=fcout_w[o2*128+64+l];
    float fb=fcout_b[o2];
    #pragma unroll
    for (int r=0;r<R;++r){
      float p = h[r]*wa + ctx[r]*wb;
      for (int o=32;o;o>>=1) p += __shfl_xor(p,o);
      if (l==o2) out[(size_t)(brow+r)*OUT_+o2] = p+fb;
    }
  }
}

extern "C" void kernel_launch(void* const* d_in, const int* in_sizes, int n_in,
                              void* d_out, int out_size, void* d_ws, size_t ws_size,
                              hipStream_t stream) {
  const float* x          = (const float*)d_in[0];
  const float* y_hist     = (const float*)d_in[1];
  const float* h0_enc     = (const float*)d_in[2];
  const float* c0_enc     = (const float*)d_in[3];
  const float* h0_dec     = (const float*)d_in[4];
  const float* c0_dec     = (const float*)d_in[5];
  const float* enc_attn_w = (const float*)d_in[6];
  const float* enc_Wih    = (const float*)d_in[8];
  const float* enc_Whh    = (const float*)d_in[9];
  const float* enc_bih    = (const float*)d_in[10];
  const float* enc_bhh    = (const float*)d_in[11];
  const float* dec_attn_w1= (const float*)d_in[12];
  const float* dec_attn_b1= (const float*)d_in[13];
  const float* dec_attn_w2= (const float*)d_in[14];
  const float* dec_Wih    = (const float*)d_in[16];
  const float* dec_Whh    = (const float*)d_in[17];
  const float* dec_bih    = (const float*)d_in[18];
  const float* dec_bhh    = (const float*)d_in[19];
  const float* fc_w       = (const float*)d_in[20];
  const float* fc_b       = (const float*)d_in[21];
  const float* fcout_w    = (const float*)d_in[22];
  const float* fcout_b    = (const float*)d_in[23];
  float* ws = (float*)d_ws;
  float* out = (float*)d_out;
  uint2* Gp = (uint2*)((uint*)d_ws + WS_G);

  hipLaunchKernelGGL(prep_kernel, dim3(128), dim3(256), 0, stream,
                     enc_Wih, enc_Whh, enc_bih, enc_bhh,
                     dec_Wih, dec_Whh, dec_bih, dec_bhh,
                     dec_attn_w1, ws);
  hipLaunchKernelGGL(gemmG_kernel, dim3(B_/8), dim3(256), 0, stream,
                     x, enc_attn_w, ws, Gp);
  hipLaunchKernelGGL(darnn_kernel, dim3(B_/(4*R)), dim3(256), 0, stream,
                     y_hist, h0_enc, c0_enc, h0_dec, c0_dec,
                     dec_attn_b1, dec_attn_w2,
                     fc_w, fc_b, fcout_w, fcout_b, ws, Gp, out);
}